// Round 4
// baseline (169.899 us; speedup 1.0000x reference)
//
#include <hip/hip_runtime.h>
#include <hip/hip_bf16.h>

// Problem constants (fixed by the reference setup)
#define N_ROWS   500000
#define NR1      25        // nr + 1
#define NGROUPS  20000     // N_ROWS / NR1
#define KCTX     20        // K context indices
#define H        128
#define NODES    10000
#define IDX_COLS 23        // 3 + K

typedef __attribute__((ext_vector_type(8))) short short8;   // 8 bf16 = 4 VGPRs
typedef __attribute__((ext_vector_type(4))) float f32x4;    // MFMA C/D

// pack two floats -> two bf16 (RNE) as a 32-bit word
__device__ __forceinline__ unsigned pkbf(float lo, float hi) {
  __hip_bfloat162 h = __float22bfloat162_rn(make_float2(lo, hi));
  union { __hip_bfloat162 h; unsigned u; } c; c.h = h;
  return c.u;
}
// bf16-pair word -> two floats (1 VALU each)
__device__ __forceinline__ float lo2f(unsigned u) {
  union { unsigned u; float f; } c; c.u = u << 16; return c.f;
}
__device__ __forceinline__ float hi2f(unsigned u) {
  union { unsigned u; float f; } c; c.u = u & 0xffff0000u; return c.f;
}

// ---------------------------------------------------------------------------
// Kernel 0: per-group context means of x -> gm bf16 [NGROUPS][H].
//  (linearity: mean(x[set]) @ W13.T == mean(x[set] @ W13.T))
// ---------------------------------------------------------------------------
#define GPB 8
#define MEAN_BLOCKS (NGROUPS / GPB)   // 2500
__global__ __launch_bounds__(256) void k_means(
    const int* __restrict__ indices, const float* __restrict__ x,
    unsigned short* __restrict__ gm) {
  const int tid = threadIdx.x;
  const int sub = tid >> 6;          // wave id: group selector
  const int jj  = (tid & 63) * 2;    // 2 cols per lane
#pragma unroll
  for (int it = 0; it < GPB / 4; ++it) {
    const int g = blockIdx.x * GPB + it * 4 + sub;
    const int* __restrict__ rowidx =
        indices + (size_t)g * NR1 * IDX_COLS + 3;    // wave-uniform -> s_load
    float s0 = 0.f, s1 = 0.f;
    int cnt = 0;
#pragma unroll
    for (int c = 0; c < KCTX; ++c) {
      const int idx = rowidx[c];
      const float2 v = *(const float2*)(x + (size_t)idx * H + jj);
      s0 += v.x; s1 += v.y;
      cnt += (idx > 0) ? 1 : 0;
    }
    const float rn = 1.f / (float)((cnt > 1) ? cnt : 1);
    *(unsigned*)(gm + (size_t)g * H + jj) = pkbf(s0 * rn, s1 * rn);
  }
}

// ---------------------------------------------------------------------------
// Kernel A (v8): flattened-grid precompute, 1255 blocks.
//  blocks [0,314)      : P1 = x @ W10.T   (157 tbase x 2 ct-halves)
//  blocks [314,628)    : P2 = x @ W11.T
//  blocks [628,1254)   : Pg = gm @ W13.T + b1  (f32)
//  block  1254         : w2f pack (W2 f32 -> bf16 in MFMA-fragment order)
//  idx2-pack path DELETED (k_main reads indices[:,0:1] directly).
// ---------------------------------------------------------------------------
#define PN 64
#define PBLK  ((NODES + PN - 1) / PN)      // 157
#define GBLK  ((NGROUPS + PN - 1) / PN)    // 313
#define B_PG  (4 * PBLK)                   // 628
#define B_W2F (B_PG + 2 * GBLK)            // 1254
#define PRE_BLOCKS (B_W2F + 1)             // 1255

__global__ __launch_bounds__(256) void k_precompute(
    const float* __restrict__ x, const float* __restrict__ W1,
    const float* __restrict__ b1, const unsigned short* __restrict__ gm,
    const float* __restrict__ W2,
    unsigned short* __restrict__ Pb, float* __restrict__ Pg,
    unsigned short* __restrict__ w2f) {
  const int tid = threadIdx.x;
  const int bid = blockIdx.x;

  const int lane = tid & 63;
  const int wvid = tid >> 6;
  const int col  = lane & 15;
  const int quad = lane >> 4;

  if (bid == B_W2F) {
    // pack W2 into fragment order: frag fi=(kt*4+ct), lane -> 8 bf16 covering
    // W2[ct*16+col][kt*32+quad*8 .. +8]. 16 KB total; L1-resident in k_main.
#pragma unroll
    for (int i = 0; i < 4; ++i) {
      const int fi = i * 4 + wvid;         // 0..15
      const int kt = fi >> 2, ct = fi & 3;
      const float* __restrict__ src =
          W2 + (size_t)(ct * 16 + col) * H + kt * 32 + quad * 8;
      const float4 v0 = *(const float4*)src;
      const float4 v1 = *(const float4*)(src + 4);
      union { short8 v; unsigned u[4]; } pk;
      pk.u[0] = pkbf(v0.x, v0.y);
      pk.u[1] = pkbf(v0.z, v0.w);
      pk.u[2] = pkbf(v1.x, v1.y);
      pk.u[3] = pkbf(v1.z, v1.w);
      *(short8*)(w2f + (size_t)(fi * 64 + lane) * 8) = pk.v;
    }
    return;
  }

  __shared__ __align__(16) short wlds[64 * 128];   // 16 KB, XOR-swizzled

  const bool isPg = (bid >= B_PG);
  int m, sub;
  if (isPg) { m = 2; sub = bid - B_PG; }
  else      { m = bid / (2 * PBLK); sub = bid - m * (2 * PBLK); }
  const int tbase = (sub >> 1) * PN;       // node/group tile base
  const int ch    = sub & 1;               // which 64-output half

  // ---- stage W1m rows [ch*64, ch*64+64) x 128 cols -> LDS bf16, swizzled ----
#pragma unroll
  for (int it = 0; it < 8; ++it) {
    const int f  = it * 256 + tid;         // 0..2047
    const int j  = f >> 5;                 // 0..63 : LDS row
    const int q4 = f & 31;                 // float4 index in source row
    const float4 v =
        *(const float4*)(W1 + (size_t)(ch * 64 + j) * (3 * H) + m * H + q4 * 4);
    const int sidx = j * 128 + (((q4 >> 1) ^ (j & 7)) << 3) + (q4 & 1) * 4;
    *(unsigned*)&wlds[sidx]     = pkbf(v.x, v.y);
    *(unsigned*)&wlds[sidx + 2] = pkbf(v.z, v.w);
  }
  __syncthreads();

  // ---- A fragments: x rows (packed) or gm rows (already bf16) ----
  short8 Af[4];
  if (isPg) {
    int g = tbase + wvid * 16 + col;
    if (g > NGROUPS - 1) g = NGROUPS - 1;
    const short8* __restrict__ gr = (const short8*)(gm + (size_t)g * H);
#pragma unroll
    for (int kt = 0; kt < 4; ++kt) Af[kt] = gr[kt * 4 + quad];
  } else {
    int node = tbase + wvid * 16 + col;
    if (node > NODES - 1) node = NODES - 1;
    const float4* __restrict__ xr = (const float4*)(x + (size_t)node * H);
#pragma unroll
    for (int kt = 0; kt < 4; ++kt) {
      const int f4 = kt * 8 + quad * 2;
      const float4 v0 = xr[f4], v1 = xr[f4 + 1];
      union { short8 v; unsigned u[4]; } pk;
      pk.u[0] = pkbf(v0.x, v0.y);
      pk.u[1] = pkbf(v0.z, v0.w);
      pk.u[2] = pkbf(v1.x, v1.y);
      pk.u[3] = pkbf(v1.z, v1.w);
      Af[kt] = pk.v;
    }
  }

  f32x4 acc[4];
#pragma unroll
  for (int ct = 0; ct < 4; ++ct) acc[ct] = (f32x4)(0.f);

#pragma unroll
  for (int kt = 0; kt < 4; ++kt) {
#pragma unroll
    for (int ct = 0; ct < 4; ++ct) {
      const int brow = ct * 16 + col;
      const short8 Bf = *(const short8*)
          &wlds[brow * 128 + (((kt * 4 + quad) ^ (brow & 7)) << 3)];
      acc[ct] = __builtin_amdgcn_mfma_f32_16x16x32_bf16(Af[kt], Bf, acc[ct], 0, 0, 0);
    }
  }

  if (isPg) {
    float b1v[4];
#pragma unroll
    for (int ct = 0; ct < 4; ++ct) b1v[ct] = b1[ch * 64 + ct * 16 + col];
#pragma unroll
    for (int reg = 0; reg < 4; ++reg) {
      const int g = tbase + wvid * 16 + quad * 4 + reg;
      if (g < NGROUPS) {
#pragma unroll
        for (int ct = 0; ct < 4; ++ct)
          Pg[(size_t)g * H + ch * 64 + ct * 16 + col] = acc[ct][reg] + b1v[ct];
      }
    }
  } else {
    unsigned short* __restrict__ Pm = Pb + (size_t)m * NODES * H;
#pragma unroll
    for (int reg = 0; reg < 4; ++reg) {
      const int n = tbase + wvid * 16 + quad * 4 + reg;
      if (n < NODES) {
#pragma unroll
        for (int ct = 0; ct < 4; ++ct) {
          union { unsigned u; unsigned short s[2]; } c;
          c.u = pkbf(acc[ct][reg], 0.f);
          Pm[(size_t)n * H + ch * 64 + ct * 16 + col] = c.s[0];
        }
      }
    }
  }
}

// ---------------------------------------------------------------------------
// Kernel C (v15): BARRIER-FREE, LDS-FREE main kernel.
//  R3 post-mortem: occupancy pinned at ~2.3 waves/SIMD across 3 block
//  structures -> the barrier+staging block topology itself was the bound
//  (~20 us/block by Little's law; aggregate VALU/L2/HBM floors all <15 us).
//  v15: each WAVE independently owns 16 rows. No __syncthreads, no LDS.
//   - B-frags JIT-loaded from w2f (16 KB, fragment-ordered, L1-resident)
//   - ctx read directly from f32 Pg (broadcast within quad, L2-hot)
//   - i0/i1 read directly from indices (idx2 table + pack kernel deleted)
//  __launch_bounds__(256,4): VGPR<=128 -> 4 waves/SIMD; independent retire.
// ---------------------------------------------------------------------------
__global__ __launch_bounds__(256, 4) void k_main(
    const int* __restrict__ indices,
    const unsigned short* __restrict__ P1b, const unsigned short* __restrict__ P2b,
    const float* __restrict__ Pg, const unsigned short* __restrict__ w2f,
    const float* __restrict__ b2, const float* __restrict__ W3,
    const float* __restrict__ b3, float* __restrict__ out) {
  const int tid  = threadIdx.x;
  const int lane = tid & 63;
  const int wv   = tid >> 6;
  const int col  = lane & 15;
  const int quad = lane >> 4;

  const int Rw = (blockIdx.x * 4 + wv) * 16;   // this wave's 16 rows
  const int r  = Rw + col;
  const int rc = (r < N_ROWS) ? r : (N_ROWS - 1);

  // ---- row indices (direct; 2 dword loads, stride-92B stream) ----
  const int i0 = indices[(size_t)rc * IDX_COLS + 0];
  const int i1 = indices[(size_t)rc * IDX_COLS + 1];
  const int g  = rc / NR1;                     // magic-mul division

  // ---- 8 independent 16B gathers (P1/P2 rows, L2-resident tables) ----
  const short8* __restrict__ pa = (const short8*)(P1b + (size_t)i0 * H);
  const short8* __restrict__ pb = (const short8*)(P2b + (size_t)i1 * H);
  short8 ua[4], ub[4];
#pragma unroll
  for (int kt = 0; kt < 4; ++kt) {
    ua[kt] = pa[kt * 4 + quad];
    ub[kt] = pb[kt * 4 + quad];
  }

  // ---- ctx row slice (b1 folded), f32, broadcast-heavy within quad ----
  const float* __restrict__ cg = Pg + (size_t)g * H;
  float4 c0[4], c1[4];
#pragma unroll
  for (int kt = 0; kt < 4; ++kt) {
    c0[kt] = *(const float4*)(cg + kt * 32 + quad * 8);
    c1[kt] = *(const float4*)(cg + kt * 32 + quad * 8 + 4);
  }

  // ---- epilogue constants (L1-hot) ----
  float b2v[4], w3v[4];
#pragma unroll
  for (int ct = 0; ct < 4; ++ct) {
    b2v[ct] = b2[ct * 16 + col];
    w3v[ct] = W3[ct * 16 + col];
  }
  const float bias3 = b3[0];

  // ---- A-build: relu(P1[i0] + P2[i1] + ctx) -> bf16 fragments ----
  short8 A[4];
#pragma unroll
  for (int kt = 0; kt < 4; ++kt) {
    union { short8 v; unsigned u[4]; } va, vb;
    va.v = ua[kt]; vb.v = ub[kt];
    const float h0 = fmaxf(lo2f(va.u[0]) + lo2f(vb.u[0]) + c0[kt].x, 0.f);
    const float h1 = fmaxf(hi2f(va.u[0]) + hi2f(vb.u[0]) + c0[kt].y, 0.f);
    const float h2 = fmaxf(lo2f(va.u[1]) + lo2f(vb.u[1]) + c0[kt].z, 0.f);
    const float h3 = fmaxf(hi2f(va.u[1]) + hi2f(vb.u[1]) + c0[kt].w, 0.f);
    const float h4 = fmaxf(lo2f(va.u[2]) + lo2f(vb.u[2]) + c1[kt].x, 0.f);
    const float h5 = fmaxf(hi2f(va.u[2]) + hi2f(vb.u[2]) + c1[kt].y, 0.f);
    const float h6 = fmaxf(lo2f(va.u[3]) + lo2f(vb.u[3]) + c1[kt].z, 0.f);
    const float h7 = fmaxf(hi2f(va.u[3]) + hi2f(vb.u[3]) + c1[kt].w, 0.f);
    union { short8 v; unsigned u[4]; } pk;
    pk.u[0] = pkbf(h0, h1);
    pk.u[1] = pkbf(h2, h3);
    pk.u[2] = pkbf(h4, h5);
    pk.u[3] = pkbf(h6, h7);
    A[kt] = pk.v;
  }

  // ---- MFMA layer 2, B-frags JIT from w2f (L1-hot 16 KB) ----
  f32x4 acc[4];
#pragma unroll
  for (int ct = 0; ct < 4; ++ct) acc[ct] = (f32x4)(0.f);
#pragma unroll
  for (int kt = 0; kt < 4; ++kt) {
#pragma unroll
    for (int ct = 0; ct < 4; ++ct) {
      const short8 Bf =
          *(const short8*)(w2f + (size_t)((kt * 4 + ct) * 64 + lane) * 8);
      acc[ct] = __builtin_amdgcn_mfma_f32_16x16x32_bf16(A[kt], Bf, acc[ct], 0, 0, 0);
    }
  }

  // ---- epilogue: relu(acc+b2) @ W3 + b3, reduce over 16 cols, store ----
#pragma unroll
  for (int reg = 0; reg < 4; ++reg) {
    float s = 0.f;
#pragma unroll
    for (int ct = 0; ct < 4; ++ct)
      s += fmaxf(acc[ct][reg] + b2v[ct], 0.f) * w3v[ct];
    s += __shfl_xor(s, 1);
    s += __shfl_xor(s, 2);
    s += __shfl_xor(s, 4);
    s += __shfl_xor(s, 8);
    if (col == 0) {
      const int row = Rw + quad * 4 + reg;     // C row = quad*4+reg
      if (row < N_ROWS) out[row] = s + bias3;
    }
  }
}

// ---------------------------------------------------------------------------
extern "C" void kernel_launch(void* const* d_in, const int* in_sizes, int n_in,
                              void* d_out, int out_size, void* d_ws, size_t ws_size,
                              hipStream_t stream) {
  const int*   indices = (const int*)  d_in[0];
  // d_in[1] = nr (scalar, fixed at 24)
  const float* x  = (const float*)d_in[2];
  const float* W1 = (const float*)d_in[3];
  const float* b1 = (const float*)d_in[4];
  const float* W2 = (const float*)d_in[5];
  const float* b2 = (const float*)d_in[6];
  const float* W3 = (const float*)d_in[7];
  const float* b3 = (const float*)d_in[8];
  float* out = (float*)d_out;

  // Workspace: P1 | P2 (bf16, 2.56 MB each) | gm (bf16, 5.12 MB)
  //            | Pg (f32, 10.24 MB) | w2f (bf16, 16 KB)  => ~20.5 MB
  unsigned short* Pb  = (unsigned short*)d_ws;
  unsigned short* P1b = Pb;
  unsigned short* P2b = Pb + (size_t)NODES * H;
  unsigned short* gm  = Pb + (size_t)2 * NODES * H;
  float* Pg = (float*)(gm + (size_t)NGROUPS * H);
  unsigned short* w2f = (unsigned short*)(Pg + (size_t)NGROUPS * H);

  k_means<<<MEAN_BLOCKS, 256, 0, stream>>>(indices, x, gm);
  k_precompute<<<PRE_BLOCKS, 256, 0, stream>>>(x, W1, b1, gm, W2, Pb, Pg, w2f);
  k_main<<<(N_ROWS + 63) / 64, 256, 0, stream>>>(indices, P1b, P2b, Pg, w2f,
                                                 b2, W3, b3, out);
}

// Round 5
// 149.790 us; speedup vs baseline: 1.1342x; 1.1342x over previous
//
#include <hip/hip_runtime.h>
#include <hip/hip_bf16.h>

// Problem constants (fixed by the reference setup)
#define N_ROWS   500000
#define NR1      25        // nr + 1
#define NGROUPS  20000     // N_ROWS / NR1
#define KCTX     20        // K context indices
#define H        128
#define NODES    10000
#define IDX_COLS 23        // 3 + K

typedef __attribute__((ext_vector_type(8))) short short8;   // 8 bf16 = 4 VGPRs
typedef __attribute__((ext_vector_type(4))) float f32x4;    // MFMA C/D

// pack two floats -> two bf16 (RNE) as a 32-bit word
__device__ __forceinline__ unsigned pkbf(float lo, float hi) {
  __hip_bfloat162 h = __float22bfloat162_rn(make_float2(lo, hi));
  union { __hip_bfloat162 h; unsigned u; } c; c.h = h;
  return c.u;
}
// bf16-pair word -> two floats (1 VALU each)
__device__ __forceinline__ float lo2f(unsigned u) {
  union { unsigned u; float f; } c; c.u = u << 16; return c.f;
}
__device__ __forceinline__ float hi2f(unsigned u) {
  union { unsigned u; float f; } c; c.u = u & 0xffff0000u; return c.f;
}

// ---------------------------------------------------------------------------
// Kernel A (v9): precompute P1/P2/P3 slices + w2f pack. 943 blocks.
//  blocks [0,314)    : P1 = x @ W10.T  (157 tbase x 2 ct-halves, bf16)
//  blocks [314,628)  : P2 = x @ W11.T
//  blocks [628,942)  : P3 = x @ W13.T  (= U; ctx means taken over U by k_ctx —
//                      linearity: mean(x[set]) @ W13.T == mean(x[set]@W13.T))
//  block  942        : w2f pack (W2 f32 -> bf16 in MFMA-fragment order)
//  gm table + Pg-GEMM (20000x128x128) DELETED vs v8.
// ---------------------------------------------------------------------------
#define PN 64
#define PBLK  ((NODES + PN - 1) / PN)      // 157
#define B_W2F (6 * PBLK)                   // 942
#define PRE_BLOCKS (B_W2F + 1)             // 943

__global__ __launch_bounds__(256) void k_precompute(
    const float* __restrict__ x, const float* __restrict__ W1,
    const float* __restrict__ W2,
    unsigned short* __restrict__ Pb, unsigned short* __restrict__ w2f) {
  const int tid = threadIdx.x;
  const int bid = blockIdx.x;

  const int lane = tid & 63;
  const int wvid = tid >> 6;
  const int col  = lane & 15;
  const int quad = lane >> 4;

  if (bid == B_W2F) {
    // pack W2 into fragment order: frag fi=(kt*4+ct), lane -> 8 bf16 covering
    // W2[ct*16+col][kt*32+quad*8 .. +8]. 16 KB total; k_main stages it to LDS.
#pragma unroll
    for (int i = 0; i < 4; ++i) {
      const int fi = i * 4 + wvid;         // 0..15
      const int kt = fi >> 2, ct = fi & 3;
      const float* __restrict__ src =
          W2 + (size_t)(ct * 16 + col) * H + kt * 32 + quad * 8;
      const float4 v0 = *(const float4*)src;
      const float4 v1 = *(const float4*)(src + 4);
      union { short8 v; unsigned u[4]; } pk;
      pk.u[0] = pkbf(v0.x, v0.y);
      pk.u[1] = pkbf(v0.z, v0.w);
      pk.u[2] = pkbf(v1.x, v1.y);
      pk.u[3] = pkbf(v1.z, v1.w);
      *(short8*)(w2f + (size_t)(fi * 64 + lane) * 8) = pk.v;
    }
    return;
  }

  __shared__ __align__(16) short wlds[64 * 128];   // 16 KB, XOR-swizzled

  const int m   = bid / (2 * PBLK);        // 0,1,2 -> W1 column slice
  const int sub = bid - m * (2 * PBLK);
  const int mcol = (m == 2) ? 2 : m;       // W1 col offset: slices 0,1,2 of 3H
  const int tbase = (sub >> 1) * PN;       // node tile base
  const int ch    = sub & 1;               // which 64-output half

  // ---- stage W1m rows [ch*64, ch*64+64) x 128 cols -> LDS bf16, swizzled ----
#pragma unroll
  for (int it = 0; it < 8; ++it) {
    const int f  = it * 256 + tid;         // 0..2047
    const int j  = f >> 5;                 // 0..63 : LDS row
    const int q4 = f & 31;                 // float4 index in source row
    const float4 v =
        *(const float4*)(W1 + (size_t)(ch * 64 + j) * (3 * H) + mcol * H + q4 * 4);
    const int sidx = j * 128 + (((q4 >> 1) ^ (j & 7)) << 3) + (q4 & 1) * 4;
    *(unsigned*)&wlds[sidx]     = pkbf(v.x, v.y);
    *(unsigned*)&wlds[sidx + 2] = pkbf(v.z, v.w);
  }
  __syncthreads();

  // ---- A fragments: x rows packed to bf16 ----
  int node = tbase + wvid * 16 + col;
  if (node > NODES - 1) node = NODES - 1;
  const float4* __restrict__ xr = (const float4*)(x + (size_t)node * H);
  short8 Af[4];
#pragma unroll
  for (int kt = 0; kt < 4; ++kt) {
    const int f4 = kt * 8 + quad * 2;
    const float4 v0 = xr[f4], v1 = xr[f4 + 1];
    union { short8 v; unsigned u[4]; } pk;
    pk.u[0] = pkbf(v0.x, v0.y);
    pk.u[1] = pkbf(v0.z, v0.w);
    pk.u[2] = pkbf(v1.x, v1.y);
    pk.u[3] = pkbf(v1.z, v1.w);
    Af[kt] = pk.v;
  }

  f32x4 acc[4];
#pragma unroll
  for (int ct = 0; ct < 4; ++ct) acc[ct] = (f32x4)(0.f);

#pragma unroll
  for (int kt = 0; kt < 4; ++kt) {
#pragma unroll
    for (int ct = 0; ct < 4; ++ct) {
      const int brow = ct * 16 + col;
      const short8 Bf = *(const short8*)
          &wlds[brow * 128 + (((kt * 4 + quad) ^ (brow & 7)) << 3)];
      acc[ct] = __builtin_amdgcn_mfma_f32_16x16x32_bf16(Af[kt], Bf, acc[ct], 0, 0, 0);
    }
  }

  unsigned short* __restrict__ Pm = Pb + (size_t)m * NODES * H;
#pragma unroll
  for (int reg = 0; reg < 4; ++reg) {
    const int n = tbase + wvid * 16 + quad * 4 + reg;
    if (n < NODES) {
#pragma unroll
      for (int ct = 0; ct < 4; ++ct) {
        union { unsigned u; unsigned short s[2]; } c;
        c.u = pkbf(acc[ct][reg], 0.f);
        Pm[(size_t)n * H + ch * 64 + ct * 16 + col] = c.s[0];
      }
    }
  }
}

// ---------------------------------------------------------------------------
// Kernel B (new): ctx means over U(=P3, bf16) -> Pg bf16 (b1 folded).
//  Replaces k_means-over-x + Pg GEMM: gathers bf16 U rows (256 B vs 512 B for
//  f32 x -> half the cache-line traffic), no 20000x128x128 GEMM, no gm table.
//  Per wave: 2 groups x 20 row-gathers (1 dword/lane) + 1 packed store.
// ---------------------------------------------------------------------------
#define GPB 8
#define CTX_BLOCKS (NGROUPS / GPB)   // 2500
__global__ __launch_bounds__(256) void k_ctx(
    const int* __restrict__ indices, const unsigned short* __restrict__ P3b,
    const float* __restrict__ b1, unsigned short* __restrict__ Pgb) {
  const int tid  = threadIdx.x;
  const int sub  = tid >> 6;         // wave id: group selector
  const int lane = tid & 63;
  const int jj   = lane * 2;         // 2 cols per lane
  const float2 b1v = *(const float2*)(b1 + jj);
#pragma unroll
  for (int it = 0; it < GPB / 4; ++it) {
    const int g = blockIdx.x * GPB + it * 4 + sub;
    const int* __restrict__ rowidx =
        indices + (size_t)g * NR1 * IDX_COLS + 3;    // wave-uniform -> s_load
    float s0 = 0.f, s1 = 0.f;
    int cnt = 0;
#pragma unroll
    for (int c = 0; c < KCTX; ++c) {
      const int idx = rowidx[c];
      const unsigned w = *(const unsigned*)(P3b + (size_t)idx * H + jj);
      s0 += lo2f(w); s1 += hi2f(w);
      cnt += (idx > 0) ? 1 : 0;
    }
    const float rn = 1.f / (float)((cnt > 1) ? cnt : 1);
    *(unsigned*)(Pgb + (size_t)g * H + jj) = pkbf(b1v.x + s0 * rn, b1v.y + s1 * rn);
  }
}

// ---------------------------------------------------------------------------
// Kernel C (v16): wave-independent, 32 rows/wave, MLP-forced.
//  R4 post-mortem: VGPR=36 proved the compiler serialized the gathers
//  (load->wait->use chains); every structure lands ~65 us because waves sit
//  in s_waitcnt with ~1 request in flight. v16:
//   - stage w2f -> LDS at block START (barrier BEFORE any dep chain; removes
//     16 serialized global B-frag loads per wave from the critical path)
//   - 32 rows/wave (2 groups): 24 gathers (P1/P2/ctx x2) issued back-to-back,
//     pinned in flight by sched_barrier(0) -> true MLP (VGPR should be ~110+)
//   - ctx from Pg bf16 (same short8 gather shape as P1/P2)
// ---------------------------------------------------------------------------
#define RPW 32       // rows per wave
__global__ __launch_bounds__(256, 4) void k_main(
    const int* __restrict__ indices,
    const unsigned short* __restrict__ P1b, const unsigned short* __restrict__ P2b,
    const unsigned short* __restrict__ Pgb, const unsigned short* __restrict__ w2f,
    const float* __restrict__ b2, const float* __restrict__ W3,
    const float* __restrict__ b3, float* __restrict__ out) {
  __shared__ __align__(16) short w2s[16 * 64 * 8];   // 16 KB, fragment-ordered

  const int tid  = threadIdx.x;
  const int lane = tid & 63;
  const int wv   = tid >> 6;
  const int col  = lane & 15;
  const int quad = lane >> 4;

  // ---- stage w2f -> LDS (64 B/thread, dense) + barrier at block start ----
  {
    const short8* __restrict__ src = (const short8*)w2f;
    short8* dst = (short8*)w2s;
#pragma unroll
    for (int i = 0; i < 4; ++i) dst[i * 256 + tid] = src[i * 256 + tid];
  }
  __syncthreads();

  const int Rw = (blockIdx.x * 4 + wv) * RPW;        // this wave's 32 rows
  const int r0 = Rw + col, r1 = Rw + 16 + col;
  const int rc0 = (r0 < N_ROWS) ? r0 : (N_ROWS - 1);
  const int rc1 = (r1 < N_ROWS) ? r1 : (N_ROWS - 1);
  const int g0 = rc0 / NR1, g1 = rc1 / NR1;          // magic-mul division

  // ---- ctx gathers (independent of the indices load -> issue first) ----
  const short8* __restrict__ pc0 = (const short8*)(Pgb + (size_t)g0 * H);
  const short8* __restrict__ pc1 = (const short8*)(Pgb + (size_t)g1 * H);
  short8 uc0[4], uc1[4];
#pragma unroll
  for (int kt = 0; kt < 4; ++kt) {
    uc0[kt] = pc0[kt * 4 + quad];
    uc1[kt] = pc1[kt * 4 + quad];
  }

  // ---- row indices (int2: cols 0,1 adjacent) ----
  const int2 iA = *(const int2*)(indices + (size_t)rc0 * IDX_COLS);
  const int2 iB = *(const int2*)(indices + (size_t)rc1 * IDX_COLS);

  // ---- P1/P2 gathers, both groups, all in flight ----
  const short8* __restrict__ pa0 = (const short8*)(P1b + (size_t)iA.x * H);
  const short8* __restrict__ pb0 = (const short8*)(P2b + (size_t)iA.y * H);
  const short8* __restrict__ pa1 = (const short8*)(P1b + (size_t)iB.x * H);
  const short8* __restrict__ pb1 = (const short8*)(P2b + (size_t)iB.y * H);
  short8 ua0[4], ub0[4], ua1[4], ub1[4];
#pragma unroll
  for (int kt = 0; kt < 4; ++kt) {
    ua0[kt] = pa0[kt * 4 + quad];
    ub0[kt] = pb0[kt * 4 + quad];
    ua1[kt] = pa1[kt * 4 + quad];
    ub1[kt] = pb1[kt * 4 + quad];
  }
  __builtin_amdgcn_sched_barrier(0);   // pin: all 24 gathers issued before use

  // ---- epilogue constants (L1-hot) ----
  float b2v[4], w3v[4];
#pragma unroll
  for (int ct = 0; ct < 4; ++ct) {
    b2v[ct] = b2[ct * 16 + col];
    w3v[ct] = W3[ct * 16 + col];
  }
  const float bias3 = b3[0];

  // ---- A-build both groups: relu(P1 + P2 + ctx) -> bf16 fragments ----
  short8 A0[4], A1[4];
#pragma unroll
  for (int kt = 0; kt < 4; ++kt) {
    union { short8 v; unsigned u[4]; } va, vb, vc;
    va.v = ua0[kt]; vb.v = ub0[kt]; vc.v = uc0[kt];
    union { short8 v; unsigned u[4]; } pk;
#pragma unroll
    for (int w = 0; w < 4; ++w) {
      const float hl = fmaxf(lo2f(va.u[w]) + lo2f(vb.u[w]) + lo2f(vc.u[w]), 0.f);
      const float hh = fmaxf(hi2f(va.u[w]) + hi2f(vb.u[w]) + hi2f(vc.u[w]), 0.f);
      pk.u[w] = pkbf(hl, hh);
    }
    A0[kt] = pk.v;
  }
#pragma unroll
  for (int kt = 0; kt < 4; ++kt) {
    union { short8 v; unsigned u[4]; } va, vb, vc;
    va.v = ua1[kt]; vb.v = ub1[kt]; vc.v = uc1[kt];
    union { short8 v; unsigned u[4]; } pk;
#pragma unroll
    for (int w = 0; w < 4; ++w) {
      const float hl = fmaxf(lo2f(va.u[w]) + lo2f(vb.u[w]) + lo2f(vc.u[w]), 0.f);
      const float hh = fmaxf(hi2f(va.u[w]) + hi2f(vb.u[w]) + hi2f(vc.u[w]), 0.f);
      pk.u[w] = pkbf(hl, hh);
    }
    A1[kt] = pk.v;
  }

  // ---- MFMA layer 2: shared B-frags from LDS, both groups ----
  f32x4 acc0[4], acc1[4];
#pragma unroll
  for (int ct = 0; ct < 4; ++ct) { acc0[ct] = (f32x4)(0.f); acc1[ct] = (f32x4)(0.f); }
#pragma unroll
  for (int kt = 0; kt < 4; ++kt) {
#pragma unroll
    for (int ct = 0; ct < 4; ++ct) {
      const short8 Bf = *(const short8*)&w2s[((kt * 4 + ct) * 64 + lane) * 8];
      acc0[ct] = __builtin_amdgcn_mfma_f32_16x16x32_bf16(A0[kt], Bf, acc0[ct], 0, 0, 0);
      acc1[ct] = __builtin_amdgcn_mfma_f32_16x16x32_bf16(A1[kt], Bf, acc1[ct], 0, 0, 0);
    }
  }

  // ---- epilogue: relu(acc+b2) @ W3 + b3, reduce over 16 cols, store ----
#pragma unroll
  for (int grp = 0; grp < 2; ++grp) {
#pragma unroll
    for (int reg = 0; reg < 4; ++reg) {
      float s = 0.f;
#pragma unroll
      for (int ct = 0; ct < 4; ++ct) {
        const float a = (grp == 0) ? acc0[ct][reg] : acc1[ct][reg];
        s += fmaxf(a + b2v[ct], 0.f) * w3v[ct];
      }
      s += __shfl_xor(s, 1);
      s += __shfl_xor(s, 2);
      s += __shfl_xor(s, 4);
      s += __shfl_xor(s, 8);
      if (col == 0) {
        const int row = Rw + grp * 16 + quad * 4 + reg;   // C row = quad*4+reg
        if (row < N_ROWS) out[row] = s + bias3;
      }
    }
  }
}

// ---------------------------------------------------------------------------
extern "C" void kernel_launch(void* const* d_in, const int* in_sizes, int n_in,
                              void* d_out, int out_size, void* d_ws, size_t ws_size,
                              hipStream_t stream) {
  const int*   indices = (const int*)  d_in[0];
  // d_in[1] = nr (scalar, fixed at 24)
  const float* x  = (const float*)d_in[2];
  const float* W1 = (const float*)d_in[3];
  const float* b1 = (const float*)d_in[4];
  const float* W2 = (const float*)d_in[5];
  const float* b2 = (const float*)d_in[6];
  const float* W3 = (const float*)d_in[7];
  const float* b3 = (const float*)d_in[8];
  float* out = (float*)d_out;

  // Workspace: P1|P2|P3 (bf16, 2.56 MB each) | Pg (bf16, 5.12 MB) | w2f (16 KB)
  unsigned short* Pb  = (unsigned short*)d_ws;
  unsigned short* P1b = Pb;
  unsigned short* P2b = Pb + (size_t)NODES * H;
  unsigned short* P3b = Pb + (size_t)2 * NODES * H;
  unsigned short* Pgb = Pb + (size_t)3 * NODES * H;
  unsigned short* w2f = Pgb + (size_t)NGROUPS * H;

  k_precompute<<<PRE_BLOCKS, 256, 0, stream>>>(x, W1, W2, Pb, w2f);
  k_ctx<<<CTX_BLOCKS, 256, 0, stream>>>(indices, P3b, b1, Pgb);
  k_main<<<(N_ROWS + 4 * RPW - 1) / (4 * RPW), 256, 0, stream>>>(
      indices, P1b, P2b, Pgb, w2f, b2, W3, b3, out);
}